// Round 3
// baseline (988.041 us; speedup 1.0000x reference)
//
#include <hip/hip_runtime.h>

#define N_NODES 100000
#define N_EDGES 1200000
#define D 64
#define D2 128
#define NPB 32                        // nodes per group / per MLP block
#define NG ((N_NODES + NPB - 1) / NPB)  // 3125 groups
#define NG_PAD 3200
#define BKT_LDS 512                   // staged bucket entries (mean 384, 6.5 sd below)

// ws layout (int32 units):
//   [0]            counts  (NG_PAD)  -- zeroed each call (12.8 KB memset)
//   [NG_PAD]       offsets (NG_PAD)
//   [2*NG_PAD]     cursors (NG_PAD)
//   [3*NG_PAD]     buckets (int2 x N_EDGES)  -- (src, (edge_id<<5)|row)
// total ~9.64 MB

__global__ __launch_bounds__(256) void hist_kernel(
    const int* __restrict__ dst, int* __restrict__ counts) {
    int e = blockIdx.x * 256 + threadIdx.x;
    if (e < N_EDGES) atomicAdd(&counts[dst[e] >> 5], 1);
}

// Single-block exclusive scan over NG counters -> offsets & cursors.
__global__ __launch_bounds__(1024) void scan_kernel(
    const int* __restrict__ counts, int* __restrict__ offsets,
    int* __restrict__ cursors) {
    __shared__ int s[1024];
    const int t = threadIdx.x;
    const int base = t * 4;
    int c0 = (base + 0 < NG) ? counts[base + 0] : 0;
    int c1 = (base + 1 < NG) ? counts[base + 1] : 0;
    int c2 = (base + 2 < NG) ? counts[base + 2] : 0;
    int c3 = (base + 3 < NG) ? counts[base + 3] : 0;
    int local = c0 + c1 + c2 + c3;
    s[t] = local; __syncthreads();
    for (int off = 1; off < 1024; off <<= 1) {
        int v = s[t] + ((t >= off) ? s[t - off] : 0);
        __syncthreads(); s[t] = v; __syncthreads();
    }
    int o0 = s[t] - local;            // exclusive prefix of this thread's chunk
    int o1 = o0 + c0, o2 = o1 + c1, o3 = o2 + c2;
    if (base + 0 < NG) { offsets[base + 0] = o0; cursors[base + 0] = o0; }
    if (base + 1 < NG) { offsets[base + 1] = o1; cursors[base + 1] = o1; }
    if (base + 2 < NG) { offsets[base + 2] = o2; cursors[base + 2] = o2; }
    if (base + 3 < NG) { offsets[base + 3] = o3; cursors[base + 3] = o3; }
}

__global__ __launch_bounds__(256) void bucket_kernel(
    const int* __restrict__ src, const int* __restrict__ dst,
    int* __restrict__ cursors, int2* __restrict__ buckets) {
    int e = blockIdx.x * 256 + threadIdx.x;
    if (e < N_EDGES) {
        int d = dst[e];
        int pos = atomicAdd(&cursors[d >> 5], 1);
        buckets[pos] = make_int2(src[e], (e << 5) | (d & 31));
    }
}

__device__ __forceinline__ void fma4(float4& acc, float s, const float4& w) {
    acc.x = fmaf(s, w.x, acc.x); acc.y = fmaf(s, w.y, acc.y);
    acc.z = fmaf(s, w.z, acc.z); acc.w = fmaf(s, w.w, acc.w);
}

__global__ __launch_bounds__(256) void gather_mlp_kernel(
    const float* __restrict__ nf, const float* __restrict__ ef,
    const int* __restrict__ offsets, const int* __restrict__ counts,
    const int2* __restrict__ buckets,
    const float* __restrict__ W1, const float* __restrict__ b1,
    const float* __restrict__ W2, const float* __restrict__ b2,
    float* __restrict__ out) {
    __shared__ float s_agg[NPB][D + 4];    // 8.7 KB, pad: conflict-free b128 + 2-way ds_add
    __shared__ float s_h[NPB][D2 + 4];     // 16.9 KB; aliased as bucket stage during gather
    int2* s_bkt = (int2*)&s_h[0][0];       // BKT_LDS*8 = 4 KB < sizeof(s_h)

    const int tid = threadIdx.x;
    const int lane = tid & 63;
    const int wv = tid >> 6;
    const int g = blockIdx.x;              // node group; nodes [g*32, g*32+32)
    const int off = offsets[g];
    const int cnt = counts[g];

    // zero accumulator tile
    for (int i = tid; i < NPB * (D + 4); i += 256) ((float*)s_agg)[i] = 0.0f;

    // stage bucket entries: contiguous -> fully coalesced bulk load
    const int scnt = min(cnt, BKT_LDS);
    for (int i = tid; i < scnt; i += 256) s_bkt[i] = buckets[off + i];
    __syncthreads();

    // edge-parallel gather: each wave takes a contiguous quarter, unrolled x4
    {
        const int q = (scnt + 3) >> 2;
        const int i1 = min(scnt, (wv + 1) * q);
        int i = min(scnt, wv * q);
        for (; i + 4 <= i1; i += 4) {
            int2 p0 = s_bkt[i], p1 = s_bkt[i + 1], p2 = s_bkt[i + 2], p3 = s_bkt[i + 3];
            float v0 = nf[(p0.x << 6) + lane] + ef[((p0.y >> 5) << 6) + lane];
            float v1 = nf[(p1.x << 6) + lane] + ef[((p1.y >> 5) << 6) + lane];
            float v2 = nf[(p2.x << 6) + lane] + ef[((p2.y >> 5) << 6) + lane];
            float v3 = nf[(p3.x << 6) + lane] + ef[((p3.y >> 5) << 6) + lane];
            atomicAdd(&s_agg[p0.y & 31][lane], v0);
            atomicAdd(&s_agg[p1.y & 31][lane], v1);
            atomicAdd(&s_agg[p2.y & 31][lane], v2);
            atomicAdd(&s_agg[p3.y & 31][lane], v3);
        }
        for (; i < i1; i++) {
            int2 p = s_bkt[i];
            float v = nf[(p.x << 6) + lane] + ef[((p.y >> 5) << 6) + lane];
            atomicAdd(&s_agg[p.y & 31][lane], v);
        }
        // overflow tail (cnt > BKT_LDS): straight from global, wave-strided
        for (int j = BKT_LDS + wv; j < cnt; j += 4) {
            int2 p = buckets[off + j];
            float v = nf[(p.x << 6) + lane] + ef[((p.y >> 5) << 6) + lane];
            atomicAdd(&s_agg[p.y & 31][lane], v);
        }
    }
    __syncthreads();

    // ---- layer 1: h = relu(agg @ W1 + b1), 4 nodes x 4 j per thread ----
    {
        const int jg = tid & 31, ng = tid >> 5;
        const int j0 = jg * 4, n0 = ng * 4;
        float4 bb = *(const float4*)(b1 + j0);
        float4 acc0 = bb, acc1 = bb, acc2 = bb, acc3 = bb;
        for (int d = 0; d < D; d += 4) {
            float4 a0 = *(const float4*)&s_agg[n0 + 0][d];
            float4 a1 = *(const float4*)&s_agg[n0 + 1][d];
            float4 a2 = *(const float4*)&s_agg[n0 + 2][d];
            float4 a3 = *(const float4*)&s_agg[n0 + 3][d];
            float4 w0 = *(const float4*)(W1 + (d + 0) * D2 + j0);
            float4 w1 = *(const float4*)(W1 + (d + 1) * D2 + j0);
            float4 w2 = *(const float4*)(W1 + (d + 2) * D2 + j0);
            float4 w3 = *(const float4*)(W1 + (d + 3) * D2 + j0);
            fma4(acc0, a0.x, w0); fma4(acc0, a0.y, w1); fma4(acc0, a0.z, w2); fma4(acc0, a0.w, w3);
            fma4(acc1, a1.x, w0); fma4(acc1, a1.y, w1); fma4(acc1, a1.z, w2); fma4(acc1, a1.w, w3);
            fma4(acc2, a2.x, w0); fma4(acc2, a2.y, w1); fma4(acc2, a2.z, w2); fma4(acc2, a2.w, w3);
            fma4(acc3, a3.x, w0); fma4(acc3, a3.y, w1); fma4(acc3, a3.z, w2); fma4(acc3, a3.w, w3);
        }
        __syncthreads();   // s_bkt alias dead before s_h writes
        *(float4*)&s_h[n0 + 0][j0] = make_float4(fmaxf(acc0.x,0.f), fmaxf(acc0.y,0.f), fmaxf(acc0.z,0.f), fmaxf(acc0.w,0.f));
        *(float4*)&s_h[n0 + 1][j0] = make_float4(fmaxf(acc1.x,0.f), fmaxf(acc1.y,0.f), fmaxf(acc1.z,0.f), fmaxf(acc1.w,0.f));
        *(float4*)&s_h[n0 + 2][j0] = make_float4(fmaxf(acc2.x,0.f), fmaxf(acc2.y,0.f), fmaxf(acc2.z,0.f), fmaxf(acc2.w,0.f));
        *(float4*)&s_h[n0 + 3][j0] = make_float4(fmaxf(acc3.x,0.f), fmaxf(acc3.y,0.f), fmaxf(acc3.z,0.f), fmaxf(acc3.w,0.f));
    }
    __syncthreads();

    // ---- layer 2: out = h @ W2 + b2, 2 nodes x 4 k per thread ----
    {
        const int kg = tid & 15, ng = tid >> 4;
        const int k0 = kg * 4, n0 = ng * 2;
        float4 bb = *(const float4*)(b2 + k0);
        float4 o0 = bb, o1 = bb;
        for (int j = 0; j < D2; j += 4) {
            float4 h0 = *(const float4*)&s_h[n0 + 0][j];
            float4 h1 = *(const float4*)&s_h[n0 + 1][j];
            float4 w0 = *(const float4*)(W2 + (j + 0) * D + k0);
            float4 w1 = *(const float4*)(W2 + (j + 1) * D + k0);
            float4 w2 = *(const float4*)(W2 + (j + 2) * D + k0);
            float4 w3 = *(const float4*)(W2 + (j + 3) * D + k0);
            fma4(o0, h0.x, w0); fma4(o0, h0.y, w1); fma4(o0, h0.z, w2); fma4(o0, h0.w, w3);
            fma4(o1, h1.x, w0); fma4(o1, h1.y, w1); fma4(o1, h1.z, w2); fma4(o1, h1.w, w3);
        }
        long long na = (long long)g * NPB + n0;
        *(float4*)(out + na * D + k0) = o0;
        *(float4*)(out + (na + 1) * D + k0) = o1;
    }
}

extern "C" void kernel_launch(void* const* d_in, const int* in_sizes, int n_in,
                              void* d_out, int out_size, void* d_ws, size_t ws_size,
                              hipStream_t stream) {
    const float* node_feat = (const float*)d_in[0];
    const float* edge_feat = (const float*)d_in[1];
    const int*   edge_index = (const int*)d_in[2];   // [2, E]: row0=src, row1=dst
    const float* W1 = (const float*)d_in[3];
    const float* b1 = (const float*)d_in[4];
    const float* W2 = (const float*)d_in[5];
    const float* b2 = (const float*)d_in[6];
    float* out = (float*)d_out;

    const int* src = edge_index;
    const int* dst = edge_index + N_EDGES;

    int* counts  = (int*)d_ws;
    int* offsets = counts + NG_PAD;
    int* cursors = counts + 2 * NG_PAD;
    int2* buckets = (int2*)(counts + 3 * NG_PAD);

    hipMemsetAsync(counts, 0, NG_PAD * sizeof(int), stream);

    const int eblocks = (N_EDGES + 255) / 256;
    hist_kernel<<<eblocks, 256, 0, stream>>>(dst, counts);
    scan_kernel<<<1, 1024, 0, stream>>>(counts, offsets, cursors);
    bucket_kernel<<<eblocks, 256, 0, stream>>>(src, dst, cursors, buckets);
    gather_mlp_kernel<<<NG, 256, 0, stream>>>(
        node_feat, edge_feat, offsets, counts, buckets, W1, b1, W2, b2, out);
}

// Round 4
// 666.198 us; speedup vs baseline: 1.4831x; 1.4831x over previous
//
#include <hip/hip_runtime.h>

#define N_NODES 100000
#define N_EDGES 1200000
#define D 64
#define D2 128
#define NPB 32                          // nodes per MLP block
#define NG (N_NODES / NPB)              // 3125 blocks (divides exactly)
#define SCAN_BLK 256
#define N_SCAN_BLKS ((N_NODES + SCAN_BLK - 1) / SCAN_BLK)   // 391
#define CNT_PAD 100352                  // multiple of 256, > N_NODES
#define BKT_LDS 512                     // staged entries/block (mean 384, +6.5 sd)

// ws layout (int32 units):
//   [0]            counts   (CNT_PAD)  -- zeroed each call
//   [CNT_PAD]      offsets  (CNT_PAD)  -- CSR row ptr, offsets[N_NODES]=N_EDGES
//   [2*CNT_PAD]    cursors  (CNT_PAD)
//   [3*CNT_PAD]    partials (512)
//   [3*CNT_PAD+512] scanned (512)
//   [3*CNT_PAD+1024] buckets (int2 x N_EDGES) -- (src, edge_id)
// total ~10.8 MB

__global__ __launch_bounds__(256) void hist_kernel(
    const int* __restrict__ dst, int* __restrict__ counts) {
    int e = blockIdx.x * 256 + threadIdx.x;
    if (e < N_EDGES) atomicAdd(&counts[dst[e]], 1);  // ~12-way avg contention
}

__global__ __launch_bounds__(SCAN_BLK) void scan1_kernel(
    const int* __restrict__ counts, int* __restrict__ offsets,
    int* __restrict__ partials) {
    __shared__ int s[2][SCAN_BLK];
    int t = threadIdx.x, i = blockIdx.x * SCAN_BLK + t;
    int c = (i < N_NODES) ? counts[i] : 0;
    int pin = 0;
    s[0][t] = c; __syncthreads();
    for (int off = 1; off < SCAN_BLK; off <<= 1) {
        int v = s[pin][t] + ((t >= off) ? s[pin][t - off] : 0);
        s[pin ^ 1][t] = v; pin ^= 1; __syncthreads();
    }
    int incl = s[pin][t];
    if (i < N_NODES) offsets[i] = incl - c;          // block-local exclusive
    if (t == SCAN_BLK - 1) partials[blockIdx.x] = incl;
}

__global__ __launch_bounds__(512) void scan2_kernel(
    const int* __restrict__ partials, int* __restrict__ scanned) {
    __shared__ int s[2][512];
    int t = threadIdx.x;
    int c = (t < N_SCAN_BLKS) ? partials[t] : 0;
    int pin = 0;
    s[0][t] = c; __syncthreads();
    for (int off = 1; off < 512; off <<= 1) {
        int v = s[pin][t] + ((t >= off) ? s[pin][t - off] : 0);
        s[pin ^ 1][t] = v; pin ^= 1; __syncthreads();
    }
    if (t < N_SCAN_BLKS) scanned[t] = s[pin][t] - c;  // exclusive
}

__global__ __launch_bounds__(SCAN_BLK) void scan3_kernel(
    int* __restrict__ offsets, int* __restrict__ cursors,
    const int* __restrict__ scanned) {
    int i = blockIdx.x * SCAN_BLK + threadIdx.x;
    if (i < N_NODES) {
        int o = offsets[i] + scanned[blockIdx.x];
        offsets[i] = o;
        cursors[i] = o;
        if (i == N_NODES - 1) offsets[N_NODES] = N_EDGES;  // CSR sentinel
    }
}

__global__ __launch_bounds__(256) void bucket_kernel(
    const int* __restrict__ src, const int* __restrict__ dst,
    int* __restrict__ cursors, int2* __restrict__ buckets) {
    int e = blockIdx.x * 256 + threadIdx.x;
    if (e < N_EDGES) {
        int pos = atomicAdd(&cursors[dst[e]], 1);
        buckets[pos] = make_int2(src[e], e);
    }
}

__device__ __forceinline__ void fma4(float4& acc, float s, const float4& w) {
    acc.x = fmaf(s, w.x, acc.x); acc.y = fmaf(s, w.y, acc.y);
    acc.z = fmaf(s, w.z, acc.z); acc.w = fmaf(s, w.w, acc.w);
}

__global__ __launch_bounds__(256) void gather_mlp_kernel(
    const float* __restrict__ nf, const float* __restrict__ ef,
    const int* __restrict__ offsets, const int2* __restrict__ buckets,
    const float* __restrict__ W1, const float* __restrict__ b1,
    const float* __restrict__ W2, const float* __restrict__ b2,
    float* __restrict__ out) {
    __shared__ float s_agg[NPB][D + 4];    // 8.7 KB
    __shared__ float s_h[NPB][D2 + 4];     // 16.9 KB; aliased as bucket stage
    __shared__ int s_off[NPB + 1];
    int2* s_bkt = (int2*)&s_h[0][0];       // 4 KB < sizeof(s_h)

    const int tid = threadIdx.x;
    const int lane = tid & 63;
    const int wv = tid >> 6;
    const int base = blockIdx.x * NPB;

    const int goff = offsets[base];
    const int bcnt = offsets[base + NPB] - goff;
    const int scnt = min(bcnt, BKT_LDS);

    if (tid <= NPB) s_off[tid] = offsets[base + tid];
    for (int i = tid; i < scnt; i += 256) s_bkt[i] = buckets[goff + i];
    __syncthreads();

    // ---- gather: wave owns 8 rows; 4 edges x float4/lane per wave-load ----
    const int sub = lane >> 4;             // edge slice 0..3
    const int c4 = (lane & 15) << 2;       // feature chunk

    for (int r = 0; r < 8; r++) {
        const int slot = wv * 8 + r;
        const int abs0 = s_off[slot];
        const int cnt = s_off[slot + 1] - abs0;
        const int loc0 = abs0 - goff;
        float4 accA = make_float4(0.f, 0.f, 0.f, 0.f);
        float4 accB = make_float4(0.f, 0.f, 0.f, 0.f);
        for (int i = 0; i < cnt; i += 8) {   // 8 edges/iter: 4 b128 loads in flight
            int j0 = i + sub, j1 = i + 4 + sub;
            if (j0 < cnt) {
                int lj = loc0 + j0;
                int2 p = (lj < scnt) ? s_bkt[lj] : buckets[abs0 + j0];
                float4 a = *(const float4*)(nf + (p.x << 6) + c4);
                float4 b = *(const float4*)(ef + ((long long)p.y << 6) + c4);
                accA.x += a.x + b.x; accA.y += a.y + b.y;
                accA.z += a.z + b.z; accA.w += a.w + b.w;
            }
            if (j1 < cnt) {
                int lj = loc0 + j1;
                int2 p = (lj < scnt) ? s_bkt[lj] : buckets[abs0 + j1];
                float4 a = *(const float4*)(nf + (p.x << 6) + c4);
                float4 b = *(const float4*)(ef + ((long long)p.y << 6) + c4);
                accB.x += a.x + b.x; accB.y += a.y + b.y;
                accB.z += a.z + b.z; accB.w += a.w + b.w;
            }
        }
        accA.x += accB.x; accA.y += accB.y; accA.z += accB.z; accA.w += accB.w;
        // reduce across the 4 edge slices (lanes l, l^16, l^32, l^48)
        accA.x += __shfl_xor(accA.x, 16); accA.y += __shfl_xor(accA.y, 16);
        accA.z += __shfl_xor(accA.z, 16); accA.w += __shfl_xor(accA.w, 16);
        accA.x += __shfl_xor(accA.x, 32); accA.y += __shfl_xor(accA.y, 32);
        accA.z += __shfl_xor(accA.z, 32); accA.w += __shfl_xor(accA.w, 32);
        if (sub == 0) *(float4*)&s_agg[slot][c4] = accA;
    }
    __syncthreads();   // all s_bkt reads done; s_h (alias) safe to write below

    // ---- layer 1: h = relu(agg @ W1 + b1), 4 nodes x 4 j per thread ----
    {
        const int jg = tid & 31, ng = tid >> 5;
        const int j0 = jg * 4, n0 = ng * 4;
        float4 bb = *(const float4*)(b1 + j0);
        float4 acc0 = bb, acc1 = bb, acc2 = bb, acc3 = bb;
        for (int d = 0; d < D; d += 4) {
            float4 a0 = *(const float4*)&s_agg[n0 + 0][d];
            float4 a1 = *(const float4*)&s_agg[n0 + 1][d];
            float4 a2 = *(const float4*)&s_agg[n0 + 2][d];
            float4 a3 = *(const float4*)&s_agg[n0 + 3][d];
            float4 w0 = *(const float4*)(W1 + (d + 0) * D2 + j0);
            float4 w1 = *(const float4*)(W1 + (d + 1) * D2 + j0);
            float4 w2 = *(const float4*)(W1 + (d + 2) * D2 + j0);
            float4 w3 = *(const float4*)(W1 + (d + 3) * D2 + j0);
            fma4(acc0, a0.x, w0); fma4(acc0, a0.y, w1); fma4(acc0, a0.z, w2); fma4(acc0, a0.w, w3);
            fma4(acc1, a1.x, w0); fma4(acc1, a1.y, w1); fma4(acc1, a1.z, w2); fma4(acc1, a1.w, w3);
            fma4(acc2, a2.x, w0); fma4(acc2, a2.y, w1); fma4(acc2, a2.z, w2); fma4(acc2, a2.w, w3);
            fma4(acc3, a3.x, w0); fma4(acc3, a3.y, w1); fma4(acc3, a3.z, w2); fma4(acc3, a3.w, w3);
        }
        *(float4*)&s_h[n0 + 0][j0] = make_float4(fmaxf(acc0.x,0.f), fmaxf(acc0.y,0.f), fmaxf(acc0.z,0.f), fmaxf(acc0.w,0.f));
        *(float4*)&s_h[n0 + 1][j0] = make_float4(fmaxf(acc1.x,0.f), fmaxf(acc1.y,0.f), fmaxf(acc1.z,0.f), fmaxf(acc1.w,0.f));
        *(float4*)&s_h[n0 + 2][j0] = make_float4(fmaxf(acc2.x,0.f), fmaxf(acc2.y,0.f), fmaxf(acc2.z,0.f), fmaxf(acc2.w,0.f));
        *(float4*)&s_h[n0 + 3][j0] = make_float4(fmaxf(acc3.x,0.f), fmaxf(acc3.y,0.f), fmaxf(acc3.z,0.f), fmaxf(acc3.w,0.f));
    }
    __syncthreads();

    // ---- layer 2: out = h @ W2 + b2, 2 nodes x 4 k per thread ----
    {
        const int kg = tid & 15, ng = tid >> 4;
        const int k0 = kg * 4, n0 = ng * 2;
        float4 bb = *(const float4*)(b2 + k0);
        float4 o0 = bb, o1 = bb;
        for (int j = 0; j < D2; j += 4) {
            float4 h0 = *(const float4*)&s_h[n0 + 0][j];
            float4 h1 = *(const float4*)&s_h[n0 + 1][j];
            float4 w0 = *(const float4*)(W2 + (j + 0) * D + k0);
            float4 w1 = *(const float4*)(W2 + (j + 1) * D + k0);
            float4 w2 = *(const float4*)(W2 + (j + 2) * D + k0);
            float4 w3 = *(const float4*)(W2 + (j + 3) * D + k0);
            fma4(o0, h0.x, w0); fma4(o0, h0.y, w1); fma4(o0, h0.z, w2); fma4(o0, h0.w, w3);
            fma4(o1, h1.x, w0); fma4(o1, h1.y, w1); fma4(o1, h1.z, w2); fma4(o1, h1.w, w3);
        }
        long long na = (long long)base + n0;
        *(float4*)(out + na * D + k0) = o0;
        *(float4*)(out + (na + 1) * D + k0) = o1;
    }
}

extern "C" void kernel_launch(void* const* d_in, const int* in_sizes, int n_in,
                              void* d_out, int out_size, void* d_ws, size_t ws_size,
                              hipStream_t stream) {
    const float* node_feat = (const float*)d_in[0];
    const float* edge_feat = (const float*)d_in[1];
    const int*   edge_index = (const int*)d_in[2];   // [2, E]: row0=src, row1=dst
    const float* W1 = (const float*)d_in[3];
    const float* b1 = (const float*)d_in[4];
    const float* W2 = (const float*)d_in[5];
    const float* b2 = (const float*)d_in[6];
    float* out = (float*)d_out;

    const int* src = edge_index;
    const int* dst = edge_index + N_EDGES;

    int* counts   = (int*)d_ws;
    int* offsets  = counts + CNT_PAD;
    int* cursors  = counts + 2 * CNT_PAD;
    int* partials = counts + 3 * CNT_PAD;
    int* scanned  = partials + 512;
    int2* buckets = (int2*)(scanned + 512);

    hipMemsetAsync(counts, 0, CNT_PAD * sizeof(int), stream);

    const int eblocks = (N_EDGES + 255) / 256;
    hist_kernel<<<eblocks, 256, 0, stream>>>(dst, counts);
    scan1_kernel<<<N_SCAN_BLKS, SCAN_BLK, 0, stream>>>(counts, offsets, partials);
    scan2_kernel<<<1, 512, 0, stream>>>(partials, scanned);
    scan3_kernel<<<N_SCAN_BLKS, SCAN_BLK, 0, stream>>>(offsets, cursors, scanned);
    bucket_kernel<<<eblocks, 256, 0, stream>>>(src, dst, cursors, buckets);

    gather_mlp_kernel<<<NG, 256, 0, stream>>>(
        node_feat, edge_feat, offsets, buckets, W1, b1, W2, b2, out);
}